// Round 3
// baseline (289.701 us; speedup 1.0000x reference)
//
#include <hip/hip_runtime.h>

#define N_NODES 50000
#define N_GRAPHS 128
#define HID 512

// Split-K geometry: Psum[128 x 512] = C[128 x K] * x[K x 512]
#define KSPAN  208                       // 13 k-steps of 16 per split
#define KSPLIT 241                       // ceil(50000/208)
#define KPAD   (KSPAN * KSPLIT)          // 50128 (>= N_NODES, zero tail)

// Workspace layout (16B-aligned sections)
#define C8_OFF     0
#define C8_BYTES   ((size_t)N_GRAPHS * KPAD)                 // 6,416,384
#define PSUM_OFF   (C8_OFF + C8_BYTES)
#define PSUM_BYTES ((size_t)N_GRAPHS * HID * 4)              // 262,144
#define COUNTS_OFF (PSUM_OFF + PSUM_BYTES)
#define ZERO_BYTES (COUNTS_OFF + 512)                        // zero C8+Psum+counts
#define CBF_OFF    ZERO_BYTES
#define CBF_BYTES  (2 * C8_BYTES)                            // bf16 counts
#define PART_OFF   (CBF_OFF + CBF_BYTES)
#define PART_BYTES ((size_t)KSPLIT * N_GRAPHS * HID * 4)     // 63.2 MB

typedef __attribute__((ext_vector_type(8))) short bf16x8;
typedef __attribute__((ext_vector_type(16))) float f32x16;

// ---------------------------------------------------------------------------
// Build byte-packed counts C8[g][node] (row stride KPAD) + per-graph path
// counts via LDS histogram.
// ---------------------------------------------------------------------------
__global__ __launch_bounds__(256)
void build_c_kernel(const int* __restrict__ w2, const int* __restrict__ w3,
                    const int* __restrict__ w4, const int* __restrict__ batch,
                    unsigned int* __restrict__ C32, int* __restrict__ counts) {
    __shared__ int hist[N_GRAPHS];
    const int t = threadIdx.x;
    if (t < N_GRAPHS) hist[t] = 0;
    __syncthreads();
    const int i = blockIdx.x * 256 + t;
    if (i < N_NODES) {
        const int a = w2[i];            // walk2[0][i] — path anchor
        const int g = batch[a];
        atomicAdd(&hist[g], 1);
        unsigned int* row = C32 + (size_t)g * (KPAD / 4);
        int nn[12];
        nn[0]  = a;
        nn[1]  = w2[N_NODES + i];
        nn[2]  = w2[2 * N_NODES + i];
        nn[3]  = w3[i];
        nn[4]  = w3[N_NODES + i];
        nn[5]  = w3[2 * N_NODES + i];
        nn[6]  = w3[3 * N_NODES + i];
        nn[7]  = w4[i];
        nn[8]  = w4[N_NODES + i];
        nn[9]  = w4[2 * N_NODES + i];
        nn[10] = w4[3 * N_NODES + i];
        nn[11] = w4[4 * N_NODES + i];
#pragma unroll
        for (int j = 0; j < 12; ++j) {
            const int nd = nn[j];
            atomicAdd(&row[nd >> 2], 1u << ((nd & 3) * 8));
        }
    }
    __syncthreads();
    if (t < N_GRAPHS) { const int hv = hist[t]; if (hv) atomicAdd(&counts[t], hv); }
}

// ---------------------------------------------------------------------------
// u8 counts -> bf16 (exact for <=255; truncation is exact since the integer
// mantissa fits in bf16's 8 bits). One u32 (4 counts) -> two u32 (4 bf16).
// ---------------------------------------------------------------------------
__global__ __launch_bounds__(256)
void c8_to_bf16_kernel(const unsigned int* __restrict__ C32,
                       unsigned int* __restrict__ Cbf) {
    const int i = blockIdx.x * 256 + threadIdx.x;
    const int total = N_GRAPHS * (KPAD / 4);
    if (i >= total) return;
    const unsigned v = C32[i];
    const float f0 = (float)(v & 0xFFu);
    const float f1 = (float)((v >> 8) & 0xFFu);
    const float f2 = (float)((v >> 16) & 0xFFu);
    const float f3 = (float)(v >> 24);
    Cbf[2 * i]     = (__builtin_bit_cast(unsigned, f0) >> 16) |
                     (__builtin_bit_cast(unsigned, f1) & 0xFFFF0000u);
    Cbf[2 * i + 1] = (__builtin_bit_cast(unsigned, f2) >> 16) |
                     (__builtin_bit_cast(unsigned, f3) & 0xFFFF0000u);
}

// ---------------------------------------------------------------------------
// B-fragment builder: lane reads x[k0+8h+j][col] (j=0..7), splits each fp32
// into bf16 hi + bf16 lo(residual) packed k-pairwise. For fixed j the 64
// lanes hit two full 128B lines (32 consecutive cols each) — coalesced.
// ---------------------------------------------------------------------------
template <int GUARD>
__device__ inline void make_b(const float* __restrict__ x, int k0, int h,
                              int col, bf16x8& bh, bf16x8& bl) {
    float v[8];
#pragma unroll
    for (int j = 0; j < 8; ++j) {
        const int k = k0 + 8 * h + j;
        v[j] = (!GUARD || k < N_NODES) ? x[(size_t)k * HID + col] : 0.f;
    }
    unsigned hw[4], lw[4];
#pragma unroll
    for (int j = 0; j < 4; ++j) {
        const unsigned u0 = __builtin_bit_cast(unsigned, v[2 * j]);
        const unsigned u1 = __builtin_bit_cast(unsigned, v[2 * j + 1]);
        const unsigned h0 = u0 & 0xFFFF0000u, h1 = u1 & 0xFFFF0000u;
        hw[j] = (h0 >> 16) | h1;
        const float r0 = v[2 * j] - __builtin_bit_cast(float, h0);
        const float r1 = v[2 * j + 1] - __builtin_bit_cast(float, h1);
        lw[j] = (__builtin_bit_cast(unsigned, r0) >> 16) |
                (__builtin_bit_cast(unsigned, r1) & 0xFFFF0000u);
    }
    uint4 uh = make_uint4(hw[0], hw[1], hw[2], hw[3]);
    uint4 ul = make_uint4(lw[0], lw[1], lw[2], lw[3]);
    bh = __builtin_bit_cast(bf16x8, uh);
    bl = __builtin_bit_cast(bf16x8, ul);
}

// ---------------------------------------------------------------------------
// Barrier-free split-K MFMA GEMM. No LDS. Block=256 (4 waves); wave owns
// 64 cols x all 128 graphs (4 m-tiles x 2 n-tiles of 32x32 acc). A loaded
// as bf16x8 dwordx4 straight from Cbf; B built from global x per 16-k step.
// grid=(2 col-halves, KSPLIT). Epilogue: plain stores to part[ks]
// (ATOMIC=1 falls back to atomicAdd into Psum if workspace is short).
// ---------------------------------------------------------------------------
template <int ATOMIC>
__global__ __launch_bounds__(256, 2)
void pool_gemm2_kernel(const float* __restrict__ x,
                       const unsigned int* __restrict__ Cbf,
                       float* __restrict__ dst) {
    const int t = threadIdx.x;
    const int lane = t & 63;
    const int w = t >> 6;                  // wave 0..3
    const int n = lane & 31;
    const int h = lane >> 5;
    const int colbase = (blockIdx.x * 4 + w) * 64;   // 8 groups x 64 cols
    const int ks = blockIdx.y;
    const int kbase = ks * KSPAN;

    f32x16 acc[4][2];
#pragma unroll
    for (int mt = 0; mt < 4; ++mt)
#pragma unroll
        for (int nt = 0; nt < 2; ++nt)
#pragma unroll
            for (int r = 0; r < 16; ++r) acc[mt][nt][r] = 0.f;

    const int col0 = colbase + n;

    for (int s = 0; s < KSPAN / 16; ++s) {
        const int k0 = kbase + s * 16;

        bf16x8 af[4];
#pragma unroll
        for (int mt = 0; mt < 4; ++mt) {
            const unsigned int* ap =
                Cbf + (size_t)(mt * 32 + n) * (KPAD / 2) + (unsigned)(k0 + 8 * h) / 2;
            af[mt] = __builtin_bit_cast(bf16x8, *(const uint4*)ap);
        }

        bf16x8 bh0, bl0, bh1, bl1;
        if (k0 + 16 <= N_NODES) {        // wave-uniform branch
            make_b<0>(x, k0, h, col0, bh0, bl0);
            make_b<0>(x, k0, h, col0 + 32, bh1, bl1);
        } else {
            make_b<1>(x, k0, h, col0, bh0, bl0);
            make_b<1>(x, k0, h, col0 + 32, bh1, bl1);
        }

#pragma unroll
        for (int mt = 0; mt < 4; ++mt) {
            acc[mt][0] = __builtin_amdgcn_mfma_f32_32x32x16_bf16(af[mt], bh0, acc[mt][0], 0, 0, 0);
            acc[mt][0] = __builtin_amdgcn_mfma_f32_32x32x16_bf16(af[mt], bl0, acc[mt][0], 0, 0, 0);
            acc[mt][1] = __builtin_amdgcn_mfma_f32_32x32x16_bf16(af[mt], bh1, acc[mt][1], 0, 0, 0);
            acc[mt][1] = __builtin_amdgcn_mfma_f32_32x32x16_bf16(af[mt], bl1, acc[mt][1], 0, 0, 0);
        }
    }

    // Epilogue: C/D layout col=lane&31, row=(r&3)+8*(r>>2)+4*(lane>>5)
    float* outp = ATOMIC ? dst : dst + (size_t)ks * (N_GRAPHS * HID);
#pragma unroll
    for (int mt = 0; mt < 4; ++mt)
#pragma unroll
        for (int nt = 0; nt < 2; ++nt) {
            const int col = colbase + nt * 32 + n;
#pragma unroll
            for (int r = 0; r < 16; ++r) {
                const int row = mt * 32 + (r & 3) + 8 * (r >> 2) + 4 * h;
                if (ATOMIC) atomicAdd(&outp[(size_t)row * HID + col], acc[mt][nt][r]);
                else        outp[(size_t)row * HID + col] = acc[mt][nt][r];
            }
        }
}

// ---------------------------------------------------------------------------
// Psum = sum over KSPLIT partials (coalesced streams, 4 indep chains)
// ---------------------------------------------------------------------------
__global__ __launch_bounds__(256)
void reduce_part_kernel(const float* __restrict__ part, float* __restrict__ Psum) {
    const int id = blockIdx.x * 256 + threadIdx.x;
    float s0 = 0.f, s1 = 0.f, s2 = 0.f, s3 = 0.f;
    int k = 0;
    for (; k + 4 <= KSPLIT; k += 4) {
        s0 += part[(size_t)k * (N_GRAPHS * HID) + id];
        s1 += part[(size_t)(k + 1) * (N_GRAPHS * HID) + id];
        s2 += part[(size_t)(k + 2) * (N_GRAPHS * HID) + id];
        s3 += part[(size_t)(k + 3) * (N_GRAPHS * HID) + id];
    }
    for (; k < KSPLIT; ++k) s0 += part[(size_t)k * (N_GRAPHS * HID) + id];
    Psum[id] = (s0 + s1) + (s2 + s3);
}

// ---------------------------------------------------------------------------
// out[r][c] += sum_k A[r][k] * W[k][c]  (+ 12*mask(r)*bias[c] on k-chunk 0)
// ---------------------------------------------------------------------------
__global__ __launch_bounds__(256)
void layer_gemm_kernel(const float* __restrict__ A, int lda, int scaleA,
                       const float* __restrict__ W,
                       const float* __restrict__ bias,
                       const int* __restrict__ counts,
                       float* __restrict__ out) {
    __shared__ float Alds[16][128];
    const int ct = blockIdx.x, rt = blockIdx.y, ksb = blockIdx.z;
    const int t = threadIdx.x;
    const int cc = ct * 64 + (t & 63);
    const int wv = t >> 6;
    const int k0 = ksb * 128;

    for (int idx = t; idx < 16 * 32; idx += 256) {
        const int rr = idx >> 5;
        const int kk = (idx & 31) * 4;
        const int row = rt * 16 + rr;
        float4 v = *(const float4*)&A[(size_t)row * lda + k0 + kk];
        if (scaleA) {
            const float inv = 1.f / (float)max(counts[row], 1);
            v.x *= inv; v.y *= inv; v.z *= inv; v.w *= inv;
        }
        *(float4*)&Alds[rr][kk] = v;
    }
    __syncthreads();

    const int r0 = rt * 16 + wv * 4;
    float a0 = 0.f, a1 = 0.f, a2 = 0.f, a3 = 0.f;
#pragma unroll 8
    for (int k = 0; k < 128; ++k) {
        const float wval = W[(size_t)(k0 + k) * HID + cc];
        a0 += Alds[wv * 4 + 0][k] * wval;
        a1 += Alds[wv * 4 + 1][k] * wval;
        a2 += Alds[wv * 4 + 2][k] * wval;
        a3 += Alds[wv * 4 + 3][k] * wval;
    }
    if (ksb == 0) {
        const float bc = bias[cc];
        a0 += (counts[r0 + 0] > 0 ? 12.f : 0.f) * bc;
        a1 += (counts[r0 + 1] > 0 ? 12.f : 0.f) * bc;
        a2 += (counts[r0 + 2] > 0 ? 12.f : 0.f) * bc;
        a3 += (counts[r0 + 3] > 0 ? 12.f : 0.f) * bc;
    }
    atomicAdd(&out[(size_t)(r0 + 0) * 1536 + cc], a0);
    atomicAdd(&out[(size_t)(r0 + 1) * 1536 + cc], a1);
    atomicAdd(&out[(size_t)(r0 + 2) * 1536 + cc], a2);
    atomicAdd(&out[(size_t)(r0 + 3) * 1536 + cc], a3);
}

extern "C" void kernel_launch(void* const* d_in, const int* in_sizes, int n_in,
                              void* d_out, int out_size, void* d_ws, size_t ws_size,
                              hipStream_t stream) {
    const float* x     = (const float*)d_in[0];
    const int*   w2    = (const int*)d_in[1];
    const int*   w3    = (const int*)d_in[2];
    const int*   w4    = (const int*)d_in[3];
    const int*   batch = (const int*)d_in[4];
    const float* W0    = (const float*)d_in[5];
    const float* b0    = (const float*)d_in[6];
    const float* W1    = (const float*)d_in[7];
    const float* b1    = (const float*)d_in[8];
    const float* W2    = (const float*)d_in[9];
    const float* b2    = (const float*)d_in[10];
    float* out = (float*)d_out;

    unsigned char* ws = (unsigned char*)d_ws;
    unsigned int* C32 = (unsigned int*)(ws + C8_OFF);
    float* Psum       = (float*)(ws + PSUM_OFF);
    int* counts       = (int*)(ws + COUNTS_OFF);
    unsigned int* Cbf = (unsigned int*)(ws + CBF_OFF);
    float* part       = (float*)(ws + PART_OFF);
    const bool use_part = ws_size >= PART_OFF + PART_BYTES;

    hipMemsetAsync(d_ws, 0, ZERO_BYTES, stream);      // C8 + Psum + counts
    hipMemsetAsync(d_out, 0, (size_t)out_size * 4, stream);

    build_c_kernel<<<(N_NODES + 255) / 256, 256, 0, stream>>>(w2, w3, w4, batch, C32, counts);

    const int cvt_total = N_GRAPHS * (KPAD / 4);
    c8_to_bf16_kernel<<<(cvt_total + 255) / 256, 256, 0, stream>>>(C32, Cbf);

    if (use_part) {
        pool_gemm2_kernel<0><<<dim3(2, KSPLIT), 256, 0, stream>>>(x, Cbf, part);
        reduce_part_kernel<<<256, 256, 0, stream>>>(part, Psum);
    } else {
        pool_gemm2_kernel<1><<<dim3(2, KSPLIT), 256, 0, stream>>>(x, Cbf, Psum);
    }

    layer_gemm_kernel<<<dim3(8, 8, 4), 256, 0, stream>>>(Psum, HID, 1, W0, b0, counts, out);
    layer_gemm_kernel<<<dim3(8, 8, 4), 256, 0, stream>>>(out, 1536, 0, W1, b1, counts, out + 512);
    layer_gemm_kernel<<<dim3(8, 8, 4), 256, 0, stream>>>(out + 512, 1536, 0, W2, b2, counts, out + 1024);
}

// Round 4
// 279.613 us; speedup vs baseline: 1.0361x; 1.0361x over previous
//
#include <hip/hip_runtime.h>

#define N_NODES 50000
#define N_GRAPHS 128
#define HID 512

// Split-K geometry: Psum[128 x 512] = C[128 x K] * x[K x 512]
#define KSPAN  416                       // 13 chunks of 32 per split
#define KSPLIT 121                       // 121*416 = 50336 >= 50000
#define KPAD   (KSPAN * KSPLIT)          // 50336
#define NPANEL (KPAD / 16)               // 3146 k-panels of 16

// Workspace layout (16B-aligned sections)
#define C8_OFF     0
#define C8_BYTES   ((size_t)N_GRAPHS * KPAD)                 // 6,443,008
#define PSUM_OFF   (C8_OFF + C8_BYTES)
#define PSUM_BYTES ((size_t)N_GRAPHS * HID * 4)              // 262,144
#define COUNTS_OFF (PSUM_OFF + PSUM_BYTES)
#define ZERO_BYTES (COUNTS_OFF + 512)                        // zero C8+Psum+counts
#define APACK_OFF  ZERO_BYTES
#define APACK_BYTES ((size_t)NPANEL * 4 * 64 * 16)           // 12,886,016
#define PART_OFF   (APACK_OFF + APACK_BYTES)
#define PART_BYTES ((size_t)KSPLIT * N_GRAPHS * HID * 4)     // 31.7 MB

typedef __attribute__((ext_vector_type(8))) short bf16x8;
typedef __attribute__((ext_vector_type(16))) float f32x16;
typedef const __attribute__((address_space(1))) void* gas_t;
typedef __attribute__((address_space(3))) void* las_t;

// ---------------------------------------------------------------------------
// Build byte-packed counts C8[g][node] (row stride KPAD) + per-graph path
// counts via LDS histogram.
// ---------------------------------------------------------------------------
__global__ __launch_bounds__(256)
void build_c_kernel(const int* __restrict__ w2, const int* __restrict__ w3,
                    const int* __restrict__ w4, const int* __restrict__ batch,
                    unsigned int* __restrict__ C32, int* __restrict__ counts) {
    __shared__ int hist[N_GRAPHS];
    const int t = threadIdx.x;
    if (t < N_GRAPHS) hist[t] = 0;
    __syncthreads();
    const int i = blockIdx.x * 256 + t;
    if (i < N_NODES) {
        const int a = w2[i];            // walk2[0][i] — path anchor
        const int g = batch[a];
        atomicAdd(&hist[g], 1);
        unsigned int* row = C32 + (size_t)g * (KPAD / 4);
        int nn[12];
        nn[0]  = a;
        nn[1]  = w2[N_NODES + i];
        nn[2]  = w2[2 * N_NODES + i];
        nn[3]  = w3[i];
        nn[4]  = w3[N_NODES + i];
        nn[5]  = w3[2 * N_NODES + i];
        nn[6]  = w3[3 * N_NODES + i];
        nn[7]  = w4[i];
        nn[8]  = w4[N_NODES + i];
        nn[9]  = w4[2 * N_NODES + i];
        nn[10] = w4[3 * N_NODES + i];
        nn[11] = w4[4 * N_NODES + i];
#pragma unroll
        for (int j = 0; j < 12; ++j) {
            const int nd = nn[j];
            atomicAdd(&row[nd >> 2], 1u << ((nd & 3) * 8));
        }
    }
    __syncthreads();
    if (t < N_GRAPHS) { const int hv = hist[t]; if (hv) atomicAdd(&counts[t], hv); }
}

__device__ inline unsigned pack_bf16(unsigned a, unsigned b) {
    // exact: u8 -> f32 -> truncate to bf16 (u8 mantissa fits in bf16)
    return (__builtin_bit_cast(unsigned, (float)a) >> 16) |
           (__builtin_bit_cast(unsigned, (float)b) & 0xFFFF0000u);
}

// ---------------------------------------------------------------------------
// Repack u8 counts into MFMA A-fragment order:
// Apack[(kp*4 + mt)*64 + lane] = 8 bf16 of row (mt*32 + lane&31),
// k = kp*16 + 8*(lane>>5) + 0..7.  -> pool kernel A-loads are fully
// contiguous dwordx4 (1 KB / wave-instr).
// ---------------------------------------------------------------------------
__global__ __launch_bounds__(256)
void c8_to_apack_kernel(const unsigned char* __restrict__ C8,
                        uint4* __restrict__ Apack) {
    const int kp = blockIdx.x;           // 0..NPANEL-1
    const int t = threadIdx.x;
    const int mt = t >> 6;
    const int l = t & 63;
    const int row = mt * 32 + (l & 31);
    const int k0 = kp * 16 + 8 * (l >> 5);
    const uint2 b = *(const uint2*)(C8 + (size_t)row * KPAD + k0);
    uint4 o;
    o.x = pack_bf16(b.x & 0xFFu, (b.x >> 8) & 0xFFu);
    o.y = pack_bf16((b.x >> 16) & 0xFFu, b.x >> 24);
    o.z = pack_bf16(b.y & 0xFFu, (b.y >> 8) & 0xFFu);
    o.w = pack_bf16((b.y >> 16) & 0xFFu, b.y >> 24);
    Apack[(size_t)(kp * 4 + mt) * 64 + l] = o;
}

// ---------------------------------------------------------------------------
// Split-K MFMA GEMM, m97-style staging. Block = 256 threads (4 waves),
// tile M=128 (all graphs) x N=64 cols x K=416. grid=(8 col-tiles, KSPLIT).
// Per 32-k chunk: stage x[32k x 64c] fp32 into 8 KB LDS via
// global_load_lds_dwordx4 (2 instr/wave), barrier, then 2 MFMA k-steps.
// Wave w: n-tile = w&1, m-tiles {2(w>>1), 2(w>>1)+1} -> 2 acc tiles.
// B built from LDS b32 column reads (bank = n -> conflict-free) with
// truncation to bf16 (single hi MFMA; residual dropped — error ~3e-4).
// A loaded contiguously from Apack. 4 blocks/CU.
// ---------------------------------------------------------------------------
template <int ATOMIC>
__global__ __launch_bounds__(256, 4)
void pool_gemm3_kernel(const float* __restrict__ x,
                       const uint4* __restrict__ Apack,
                       float* __restrict__ dst) {
    __shared__ float lbuf[32 * 64];
    const int t = threadIdx.x;
    const int lane = t & 63;
    const int w = t >> 6;
    const int n = lane & 31;
    const int h = lane >> 5;
    const int nt = w & 1;
    const int p = w >> 1;
    const int colbase = blockIdx.x * 64;
    const int ks = blockIdx.y;
    const int kbase = ks * KSPAN;

    f32x16 acc0, acc1;
#pragma unroll
    for (int r = 0; r < 16; ++r) { acc0[r] = 0.f; acc1[r] = 0.f; }

    for (int ch = 0; ch < KSPAN / 32; ++ch) {
        const int k0 = kbase + ch * 32;
        if (k0 >= N_NODES) break;                 // block-uniform
        if (k0 + 32 <= N_NODES) {
#pragma unroll
            for (int i = 0; i < 2; ++i) {
                const int r = w * 8 + i * 4 + (lane >> 4);
                const float* gp = x + (size_t)(k0 + r) * HID + colbase + (lane & 15) * 4;
                las_t lp = (las_t)&lbuf[(w * 8 + i * 4) * 64];
                __builtin_amdgcn_global_load_lds((gas_t)gp, lp, 16, 0, 0);
            }
        } else {                                   // tail chunk (rare)
#pragma unroll
            for (int j = 0; j < 8; ++j) {
                const int idx = t + j * 256;
                const int r = idx >> 6, c = idx & 63;
                const int kg = k0 + r;
                lbuf[idx] = (kg < N_NODES) ? x[(size_t)kg * HID + colbase + c] : 0.f;
            }
        }
        __syncthreads();

        const int kp0 = k0 >> 4;
#pragma unroll
        for (int kk = 0; kk < 2; ++kk) {
            unsigned bw[4];
#pragma unroll
            for (int j2 = 0; j2 < 4; ++j2) {
                const int kl = kk * 16 + 8 * h + 2 * j2;
                const unsigned u0 = __builtin_bit_cast(unsigned, lbuf[kl * 64 + nt * 32 + n]);
                const unsigned u1 = __builtin_bit_cast(unsigned, lbuf[(kl + 1) * 64 + nt * 32 + n]);
                bw[j2] = (u0 >> 16) | (u1 & 0xFFFF0000u);
            }
            const uint4 bu = make_uint4(bw[0], bw[1], bw[2], bw[3]);
            const bf16x8 bf = __builtin_bit_cast(bf16x8, bu);
            const bf16x8 a0 = __builtin_bit_cast(bf16x8,
                Apack[(size_t)((kp0 + kk) * 4 + 2 * p) * 64 + lane]);
            const bf16x8 a1 = __builtin_bit_cast(bf16x8,
                Apack[(size_t)((kp0 + kk) * 4 + 2 * p + 1) * 64 + lane]);
            acc0 = __builtin_amdgcn_mfma_f32_32x32x16_bf16(a0, bf, acc0, 0, 0, 0);
            acc1 = __builtin_amdgcn_mfma_f32_32x32x16_bf16(a1, bf, acc1, 0, 0, 0);
        }
        __syncthreads();
    }

    // Epilogue: C/D layout col=lane&31, row=(r&3)+8*(r>>2)+4*(lane>>5)
    float* outp = ATOMIC ? dst : dst + (size_t)ks * (N_GRAPHS * HID);
    const int col = colbase + nt * 32 + n;
#pragma unroll
    for (int r = 0; r < 16; ++r) {
        const int row0 = 2 * p * 32 + (r & 3) + 8 * (r >> 2) + 4 * h;
        if (ATOMIC) {
            atomicAdd(&outp[(size_t)row0 * HID + col], acc0[r]);
            atomicAdd(&outp[(size_t)(row0 + 32) * HID + col], acc1[r]);
        } else {
            outp[(size_t)row0 * HID + col] = acc0[r];
            outp[(size_t)(row0 + 32) * HID + col] = acc1[r];
        }
    }
}

// ---------------------------------------------------------------------------
// Psum = sum over KSPLIT partials (coalesced streams, 4 indep chains)
// ---------------------------------------------------------------------------
__global__ __launch_bounds__(256)
void reduce_part_kernel(const float* __restrict__ part, float* __restrict__ Psum) {
    const int id = blockIdx.x * 256 + threadIdx.x;
    float s0 = 0.f, s1 = 0.f, s2 = 0.f, s3 = 0.f;
    int k = 0;
    for (; k + 4 <= KSPLIT; k += 4) {
        s0 += part[(size_t)k * (N_GRAPHS * HID) + id];
        s1 += part[(size_t)(k + 1) * (N_GRAPHS * HID) + id];
        s2 += part[(size_t)(k + 2) * (N_GRAPHS * HID) + id];
        s3 += part[(size_t)(k + 3) * (N_GRAPHS * HID) + id];
    }
    for (; k < KSPLIT; ++k) s0 += part[(size_t)k * (N_GRAPHS * HID) + id];
    Psum[id] = (s0 + s1) + (s2 + s3);
}

// ---------------------------------------------------------------------------
// out[r][c] += sum_k A[r][k] * W[k][c]  (+ 12*mask(r)*bias[c] on k-chunk 0)
// ---------------------------------------------------------------------------
__global__ __launch_bounds__(256)
void layer_gemm_kernel(const float* __restrict__ A, int lda, int scaleA,
                       const float* __restrict__ W,
                       const float* __restrict__ bias,
                       const int* __restrict__ counts,
                       float* __restrict__ out) {
    __shared__ float Alds[16][128];
    const int ct = blockIdx.x, rt = blockIdx.y, ksb = blockIdx.z;
    const int t = threadIdx.x;
    const int cc = ct * 64 + (t & 63);
    const int wv = t >> 6;
    const int k0 = ksb * 128;

    for (int idx = t; idx < 16 * 32; idx += 256) {
        const int rr = idx >> 5;
        const int kk = (idx & 31) * 4;
        const int row = rt * 16 + rr;
        float4 v = *(const float4*)&A[(size_t)row * lda + k0 + kk];
        if (scaleA) {
            const float inv = 1.f / (float)max(counts[row], 1);
            v.x *= inv; v.y *= inv; v.z *= inv; v.w *= inv;
        }
        *(float4*)&Alds[rr][kk] = v;
    }
    __syncthreads();

    const int r0 = rt * 16 + wv * 4;
    float a0 = 0.f, a1 = 0.f, a2 = 0.f, a3 = 0.f;
#pragma unroll 8
    for (int k = 0; k < 128; ++k) {
        const float wval = W[(size_t)(k0 + k) * HID + cc];
        a0 += Alds[wv * 4 + 0][k] * wval;
        a1 += Alds[wv * 4 + 1][k] * wval;
        a2 += Alds[wv * 4 + 2][k] * wval;
        a3 += Alds[wv * 4 + 3][k] * wval;
    }
    if (ksb == 0) {
        const float bc = bias[cc];
        a0 += (counts[r0 + 0] > 0 ? 12.f : 0.f) * bc;
        a1 += (counts[r0 + 1] > 0 ? 12.f : 0.f) * bc;
        a2 += (counts[r0 + 2] > 0 ? 12.f : 0.f) * bc;
        a3 += (counts[r0 + 3] > 0 ? 12.f : 0.f) * bc;
    }
    atomicAdd(&out[(size_t)(r0 + 0) * 1536 + cc], a0);
    atomicAdd(&out[(size_t)(r0 + 1) * 1536 + cc], a1);
    atomicAdd(&out[(size_t)(r0 + 2) * 1536 + cc], a2);
    atomicAdd(&out[(size_t)(r0 + 3) * 1536 + cc], a3);
}

extern "C" void kernel_launch(void* const* d_in, const int* in_sizes, int n_in,
                              void* d_out, int out_size, void* d_ws, size_t ws_size,
                              hipStream_t stream) {
    const float* x     = (const float*)d_in[0];
    const int*   w2    = (const int*)d_in[1];
    const int*   w3    = (const int*)d_in[2];
    const int*   w4    = (const int*)d_in[3];
    const int*   batch = (const int*)d_in[4];
    const float* W0    = (const float*)d_in[5];
    const float* b0    = (const float*)d_in[6];
    const float* W1    = (const float*)d_in[7];
    const float* b1    = (const float*)d_in[8];
    const float* W2    = (const float*)d_in[9];
    const float* b2    = (const float*)d_in[10];
    float* out = (float*)d_out;

    unsigned char* ws  = (unsigned char*)d_ws;
    unsigned int* C32  = (unsigned int*)(ws + C8_OFF);
    float* Psum        = (float*)(ws + PSUM_OFF);
    int* counts        = (int*)(ws + COUNTS_OFF);
    uint4* Apack       = (uint4*)(ws + APACK_OFF);
    float* part        = (float*)(ws + PART_OFF);
    const bool use_part = ws_size >= PART_OFF + PART_BYTES;

    hipMemsetAsync(d_ws, 0, ZERO_BYTES, stream);      // C8 + Psum + counts
    hipMemsetAsync(d_out, 0, (size_t)out_size * 4, stream);

    build_c_kernel<<<(N_NODES + 255) / 256, 256, 0, stream>>>(w2, w3, w4, batch, C32, counts);
    c8_to_apack_kernel<<<NPANEL, 256, 0, stream>>>((const unsigned char*)C32, Apack);

    if (use_part) {
        pool_gemm3_kernel<0><<<dim3(8, KSPLIT), 256, 0, stream>>>(x, Apack, part);
        reduce_part_kernel<<<256, 256, 0, stream>>>(part, Psum);
    } else {
        pool_gemm3_kernel<1><<<dim3(8, KSPLIT), 256, 0, stream>>>(x, Apack, Psum);
    }

    layer_gemm_kernel<<<dim3(8, 8, 4), 256, 0, stream>>>(Psum, HID, 1, W0, b0, counts, out);
    layer_gemm_kernel<<<dim3(8, 8, 4), 256, 0, stream>>>(out, 1536, 0, W1, b1, counts, out + 512);
    layer_gemm_kernel<<<dim3(8, 8, 4), 256, 0, stream>>>(out + 512, 1536, 0, W2, b2, counts, out + 1024);
}

// Round 5
// 276.392 us; speedup vs baseline: 1.0482x; 1.0117x over previous
//
#include <hip/hip_runtime.h>

#define N_NODES 50000
#define N_GRAPHS 128
#define HID 512

// Split-K geometry: Psum[128 x 512] = C[128 x K] * x[K x 512]
#define KSPAN  512                       // 4 chunks of 128 rows per split
#define KSPLIT 98                        // 98*512 = 50176 >= 50000
#define KPAD   (KSPAN * KSPLIT)          // 50176
#define NPANEL (KPAD / 16)               // 3136 k-panels of 16

// Workspace layout (16B-aligned sections)
#define C8_OFF     0
#define C8_BYTES   ((size_t)N_GRAPHS * KPAD)                 // 6,422,528
#define PSUM_OFF   (C8_OFF + C8_BYTES)
#define PSUM_BYTES ((size_t)N_GRAPHS * HID * 4)              // 262,144
#define COUNTS_OFF (PSUM_OFF + PSUM_BYTES)
#define ZERO_BYTES (COUNTS_OFF + 512)                        // zero C8+Psum+counts
#define APACK_OFF  ZERO_BYTES
#define APACK_BYTES ((size_t)NPANEL * 4 * 64 * 16)           // 12,845,056
#define PART_OFF   (APACK_OFF + APACK_BYTES)
#define PART_BYTES ((size_t)KSPLIT * N_GRAPHS * HID * 4)     // 25.7 MB

typedef __attribute__((ext_vector_type(8))) short bf16x8;
typedef __attribute__((ext_vector_type(16))) float f32x16;
typedef const __attribute__((address_space(1))) void* gas_t;
typedef __attribute__((address_space(3))) void* las_t;

// ---------------------------------------------------------------------------
// Build byte-packed counts C8[g][node] (row stride KPAD) + per-graph path
// counts via LDS histogram.
// ---------------------------------------------------------------------------
__global__ __launch_bounds__(256)
void build_c_kernel(const int* __restrict__ w2, const int* __restrict__ w3,
                    const int* __restrict__ w4, const int* __restrict__ batch,
                    unsigned int* __restrict__ C32, int* __restrict__ counts) {
    __shared__ int hist[N_GRAPHS];
    const int t = threadIdx.x;
    if (t < N_GRAPHS) hist[t] = 0;
    __syncthreads();
    const int i = blockIdx.x * 256 + t;
    if (i < N_NODES) {
        const int a = w2[i];            // walk2[0][i] — path anchor
        const int g = batch[a];
        atomicAdd(&hist[g], 1);
        unsigned int* row = C32 + (size_t)g * (KPAD / 4);
        int nn[12];
        nn[0]  = a;
        nn[1]  = w2[N_NODES + i];
        nn[2]  = w2[2 * N_NODES + i];
        nn[3]  = w3[i];
        nn[4]  = w3[N_NODES + i];
        nn[5]  = w3[2 * N_NODES + i];
        nn[6]  = w3[3 * N_NODES + i];
        nn[7]  = w4[i];
        nn[8]  = w4[N_NODES + i];
        nn[9]  = w4[2 * N_NODES + i];
        nn[10] = w4[3 * N_NODES + i];
        nn[11] = w4[4 * N_NODES + i];
#pragma unroll
        for (int j = 0; j < 12; ++j) {
            const int nd = nn[j];
            atomicAdd(&row[nd >> 2], 1u << ((nd & 3) * 8));
        }
    }
    __syncthreads();
    if (t < N_GRAPHS) { const int hv = hist[t]; if (hv) atomicAdd(&counts[t], hv); }
}

__device__ inline unsigned pack_bf16(unsigned a, unsigned b) {
    // exact: u8 -> f32 -> truncate to bf16 (u8 mantissa fits in bf16)
    return (__builtin_bit_cast(unsigned, (float)a) >> 16) |
           (__builtin_bit_cast(unsigned, (float)b) & 0xFFFF0000u);
}

// ---------------------------------------------------------------------------
// Repack u8 counts into MFMA A-fragment order:
// Apack[(kp*4 + mt)*64 + lane] = 8 bf16 of row (mt*32 + lane&31),
// k = kp*16 + 8*(lane>>5) + 0..7.
// ---------------------------------------------------------------------------
__global__ __launch_bounds__(256)
void c8_to_apack_kernel(const unsigned char* __restrict__ C8,
                        uint4* __restrict__ Apack) {
    const int kp = blockIdx.x;           // 0..NPANEL-1
    const int t = threadIdx.x;
    const int mt = t >> 6;
    const int l = t & 63;
    const int row = mt * 32 + (l & 31);
    const int k0 = kp * 16 + 8 * (l >> 5);
    const uint2 b = *(const uint2*)(C8 + (size_t)row * KPAD + k0);
    uint4 o;
    o.x = pack_bf16(b.x & 0xFFu, (b.x >> 8) & 0xFFu);
    o.y = pack_bf16((b.x >> 16) & 0xFFu, b.x >> 24);
    o.z = pack_bf16(b.y & 0xFFu, (b.y >> 8) & 0xFFu);
    o.w = pack_bf16((b.y >> 16) & 0xFFu, b.y >> 24);
    Apack[(size_t)(kp * 4 + mt) * 64 + l] = o;
}

// ---------------------------------------------------------------------------
// Split-K MFMA GEMM with BIG chunks to amortize the barrier drain.
// Block = 512 threads (8 waves), tile M=128 x N=128, KSPAN=512 processed as
// 4 chunks of 128 rows. Per chunk: stage x[128k x 128c] fp32 = 64 KB into
// LDS via 64x global_load_lds_dwordx4 (8 per wave, 64-deep MLP per drain),
// one barrier, then 8 MFMA k-steps per wave. Wave w: n-subtile nt=w&3,
// m-half mh=w>>2 (2 acc tiles). B from LDS b32 column reads (bank = n,
// conflict-free), truncated to bf16 (error ~3e-4 << 0.018 threshold).
// A loaded contiguously from Apack (L1-shared across nt-waves).
// grid=(4 col-tiles, KSPLIT) = 392 blocks, 2 blocks/CU -> one generation.
// ---------------------------------------------------------------------------
template <int ATOMIC>
__global__ __launch_bounds__(512, 4)
void pool_gemm4_kernel(const float* __restrict__ x,
                       const uint4* __restrict__ Apack,
                       float* __restrict__ dst) {
    __shared__ float lbuf[128 * 128];    // 64 KB
    const int t = threadIdx.x;
    const int lane = t & 63;
    const int w = t >> 6;                // 0..7
    const int n = lane & 31;
    const int h = lane >> 5;
    const int nt = w & 3;
    const int mh = w >> 2;               // 0..1
    const int colbase = blockIdx.x * 128;
    const int ks = blockIdx.y;
    const int kbase = ks * KSPAN;

    f32x16 acc0, acc1;
#pragma unroll
    for (int r = 0; r < 16; ++r) { acc0[r] = 0.f; acc1[r] = 0.f; }

    for (int ch = 0; ch < 4; ++ch) {
        const int k0 = kbase + ch * 128;
        if (k0 >= N_NODES) break;                 // block-uniform
        if (k0 + 128 <= N_NODES) {
#pragma unroll
            for (int i = 0; i < 8; ++i) {
                const int rbase = w * 16 + 2 * i;     // 2 rows per instr
                const float* gp = x + (size_t)(k0 + rbase + (lane >> 5)) * HID
                                    + colbase + (lane & 31) * 4;
                las_t lp = (las_t)&lbuf[rbase * 128];
                __builtin_amdgcn_global_load_lds((gas_t)gp, lp, 16, 0, 0);
            }
        } else {                                   // tail chunk (rare)
#pragma unroll
            for (int j = 0; j < 32; ++j) {
                const int idx = t + j * 512;
                const int r = idx >> 7, c = idx & 127;
                const int kg = k0 + r;
                lbuf[idx] = (kg < N_NODES) ? x[(size_t)kg * HID + colbase + c] : 0.f;
            }
        }
        __syncthreads();

        const int kp0 = k0 >> 4;
#pragma unroll
        for (int s = 0; s < 8; ++s) {
            unsigned bw[4];
#pragma unroll
            for (int j2 = 0; j2 < 4; ++j2) {
                const int kl = s * 16 + 8 * h + 2 * j2;
                const unsigned u0 = __builtin_bit_cast(unsigned, lbuf[kl * 128 + nt * 32 + n]);
                const unsigned u1 = __builtin_bit_cast(unsigned, lbuf[(kl + 1) * 128 + nt * 32 + n]);
                bw[j2] = (u0 >> 16) | (u1 & 0xFFFF0000u);
            }
            const uint4 bu = make_uint4(bw[0], bw[1], bw[2], bw[3]);
            const bf16x8 bf = __builtin_bit_cast(bf16x8, bu);
            const bf16x8 a0 = __builtin_bit_cast(bf16x8,
                Apack[(size_t)((kp0 + s) * 4 + 2 * mh) * 64 + lane]);
            const bf16x8 a1 = __builtin_bit_cast(bf16x8,
                Apack[(size_t)((kp0 + s) * 4 + 2 * mh + 1) * 64 + lane]);
            acc0 = __builtin_amdgcn_mfma_f32_32x32x16_bf16(a0, bf, acc0, 0, 0, 0);
            acc1 = __builtin_amdgcn_mfma_f32_32x32x16_bf16(a1, bf, acc1, 0, 0, 0);
        }
        __syncthreads();
    }

    // Epilogue: C/D layout col=lane&31, row=(r&3)+8*(r>>2)+4*(lane>>5)
    float* outp = ATOMIC ? dst : dst + (size_t)ks * (N_GRAPHS * HID);
    const int col = colbase + nt * 32 + n;
#pragma unroll
    for (int r = 0; r < 16; ++r) {
        const int row0 = mh * 64 + (r & 3) + 8 * (r >> 2) + 4 * h;
        if (ATOMIC) {
            atomicAdd(&outp[(size_t)row0 * HID + col], acc0[r]);
            atomicAdd(&outp[(size_t)(row0 + 32) * HID + col], acc1[r]);
        } else {
            outp[(size_t)row0 * HID + col] = acc0[r];
            outp[(size_t)(row0 + 32) * HID + col] = acc1[r];
        }
    }
}

// ---------------------------------------------------------------------------
// Psum = sum over KSPLIT partials (coalesced streams)
// ---------------------------------------------------------------------------
__global__ __launch_bounds__(256)
void reduce_part_kernel(const float* __restrict__ part, float* __restrict__ Psum) {
    const int id = blockIdx.x * 256 + threadIdx.x;
    float s0 = 0.f, s1 = 0.f;
    for (int k = 0; k + 2 <= KSPLIT; k += 2) {
        s0 += part[(size_t)k * (N_GRAPHS * HID) + id];
        s1 += part[(size_t)(k + 1) * (N_GRAPHS * HID) + id];
    }
    Psum[id] = s0 + s1;
}

// ---------------------------------------------------------------------------
// out[r][c] += sum_k A[r][k] * W[k][c]  (+ 12*mask(r)*bias[c] on k-chunk 0)
// ---------------------------------------------------------------------------
__global__ __launch_bounds__(256)
void layer_gemm_kernel(const float* __restrict__ A, int lda, int scaleA,
                       const float* __restrict__ W,
                       const float* __restrict__ bias,
                       const int* __restrict__ counts,
                       float* __restrict__ out) {
    __shared__ float Alds[16][128];
    const int ct = blockIdx.x, rt = blockIdx.y, ksb = blockIdx.z;
    const int t = threadIdx.x;
    const int cc = ct * 64 + (t & 63);
    const int wv = t >> 6;
    const int k0 = ksb * 128;

    for (int idx = t; idx < 16 * 32; idx += 256) {
        const int rr = idx >> 5;
        const int kk = (idx & 31) * 4;
        const int row = rt * 16 + rr;
        float4 v = *(const float4*)&A[(size_t)row * lda + k0 + kk];
        if (scaleA) {
            const float inv = 1.f / (float)max(counts[row], 1);
            v.x *= inv; v.y *= inv; v.z *= inv; v.w *= inv;
        }
        *(float4*)&Alds[rr][kk] = v;
    }
    __syncthreads();

    const int r0 = rt * 16 + wv * 4;
    float a0 = 0.f, a1 = 0.f, a2 = 0.f, a3 = 0.f;
#pragma unroll 8
    for (int k = 0; k < 128; ++k) {
        const float wval = W[(size_t)(k0 + k) * HID + cc];
        a0 += Alds[wv * 4 + 0][k] * wval;
        a1 += Alds[wv * 4 + 1][k] * wval;
        a2 += Alds[wv * 4 + 2][k] * wval;
        a3 += Alds[wv * 4 + 3][k] * wval;
    }
    if (ksb == 0) {
        const float bc = bias[cc];
        a0 += (counts[r0 + 0] > 0 ? 12.f : 0.f) * bc;
        a1 += (counts[r0 + 1] > 0 ? 12.f : 0.f) * bc;
        a2 += (counts[r0 + 2] > 0 ? 12.f : 0.f) * bc;
        a3 += (counts[r0 + 3] > 0 ? 12.f : 0.f) * bc;
    }
    atomicAdd(&out[(size_t)(r0 + 0) * 1536 + cc], a0);
    atomicAdd(&out[(size_t)(r0 + 1) * 1536 + cc], a1);
    atomicAdd(&out[(size_t)(r0 + 2) * 1536 + cc], a2);
    atomicAdd(&out[(size_t)(r0 + 3) * 1536 + cc], a3);
}

extern "C" void kernel_launch(void* const* d_in, const int* in_sizes, int n_in,
                              void* d_out, int out_size, void* d_ws, size_t ws_size,
                              hipStream_t stream) {
    const float* x     = (const float*)d_in[0];
    const int*   w2    = (const int*)d_in[1];
    const int*   w3    = (const int*)d_in[2];
    const int*   w4    = (const int*)d_in[3];
    const int*   batch = (const int*)d_in[4];
    const float* W0    = (const float*)d_in[5];
    const float* b0    = (const float*)d_in[6];
    const float* W1    = (const float*)d_in[7];
    const float* b1    = (const float*)d_in[8];
    const float* W2    = (const float*)d_in[9];
    const float* b2    = (const float*)d_in[10];
    float* out = (float*)d_out;

    unsigned char* ws  = (unsigned char*)d_ws;
    unsigned int* C32  = (unsigned int*)(ws + C8_OFF);
    float* Psum        = (float*)(ws + PSUM_OFF);
    int* counts        = (int*)(ws + COUNTS_OFF);
    uint4* Apack       = (uint4*)(ws + APACK_OFF);
    float* part        = (float*)(ws + PART_OFF);
    const bool use_part = ws_size >= PART_OFF + PART_BYTES;

    hipMemsetAsync(d_ws, 0, ZERO_BYTES, stream);      // C8 + Psum + counts
    hipMemsetAsync(d_out, 0, (size_t)out_size * 4, stream);

    build_c_kernel<<<(N_NODES + 255) / 256, 256, 0, stream>>>(w2, w3, w4, batch, C32, counts);
    c8_to_apack_kernel<<<NPANEL, 256, 0, stream>>>((const unsigned char*)C32, Apack);

    if (use_part) {
        pool_gemm4_kernel<0><<<dim3(4, KSPLIT), 512, 0, stream>>>(x, Apack, part);
        reduce_part_kernel<<<256, 256, 0, stream>>>(part, Psum);
    } else {
        pool_gemm4_kernel<1><<<dim3(4, KSPLIT), 512, 0, stream>>>(x, Apack, Psum);
    }

    layer_gemm_kernel<<<dim3(8, 8, 4), 256, 0, stream>>>(Psum, HID, 1, W0, b0, counts, out);
    layer_gemm_kernel<<<dim3(8, 8, 4), 256, 0, stream>>>(out, 1536, 0, W1, b1, counts, out + 512);
    layer_gemm_kernel<<<dim3(8, 8, 4), 256, 0, stream>>>(out + 512, 1536, 0, W2, b2, counts, out + 1024);
}

// Round 6
// 266.793 us; speedup vs baseline: 1.0859x; 1.0360x over previous
//
#include <hip/hip_runtime.h>

#define N_NODES 50000
#define N_GRAPHS 128
#define HID 512

// Split-K geometry: Psum[128 x 512] = C[128 x K] * x[K x 512]
#define KSPAN   288                      // 18 k-steps of 16 per wave
#define NSTEP   18
#define KS2     44                       // part slices (one per block-row)
#define KSPLIT  (KS2 * 4)                // 176 wave-level k-splits
#define KPAD    (KSPAN * KSPLIT)         // 50688
#define NPANEL  (KPAD / 16)              // 3168

// Workspace layout (16B-aligned sections)
#define C8_OFF     0
#define C8_BYTES   ((size_t)N_GRAPHS * KPAD)                 // 6,488,064
#define PSUM_OFF   (C8_OFF + C8_BYTES)
#define PSUM_BYTES ((size_t)N_GRAPHS * HID * 4)              // 262,144
#define COUNTS_OFF (PSUM_OFF + PSUM_BYTES)
#define ZERO_BYTES (COUNTS_OFF + 512)                        // zero C8+Psum+counts
#define APACK_OFF  ZERO_BYTES
#define APACK_BYTES ((size_t)NPANEL * 4 * 64 * 16)           // 12,976,128
#define PART_OFF   (APACK_OFF + APACK_BYTES)
#define PART_BYTES ((size_t)KS2 * N_GRAPHS * HID * 4)        // 11.5 MB

typedef __attribute__((ext_vector_type(8))) short bf16x8;
typedef __attribute__((ext_vector_type(16))) float f32x16;

// ---------------------------------------------------------------------------
// Build byte-packed counts C8[g][node] (row stride KPAD) + per-graph path
// counts via LDS histogram.
// ---------------------------------------------------------------------------
__global__ __launch_bounds__(256)
void build_c_kernel(const int* __restrict__ w2, const int* __restrict__ w3,
                    const int* __restrict__ w4, const int* __restrict__ batch,
                    unsigned int* __restrict__ C32, int* __restrict__ counts) {
    __shared__ int hist[N_GRAPHS];
    const int t = threadIdx.x;
    if (t < N_GRAPHS) hist[t] = 0;
    __syncthreads();
    const int i = blockIdx.x * 256 + t;
    if (i < N_NODES) {
        const int a = w2[i];            // walk2[0][i] — path anchor
        const int g = batch[a];
        atomicAdd(&hist[g], 1);
        unsigned int* row = C32 + (size_t)g * (KPAD / 4);
        int nn[12];
        nn[0]  = a;
        nn[1]  = w2[N_NODES + i];
        nn[2]  = w2[2 * N_NODES + i];
        nn[3]  = w3[i];
        nn[4]  = w3[N_NODES + i];
        nn[5]  = w3[2 * N_NODES + i];
        nn[6]  = w3[3 * N_NODES + i];
        nn[7]  = w4[i];
        nn[8]  = w4[N_NODES + i];
        nn[9]  = w4[2 * N_NODES + i];
        nn[10] = w4[3 * N_NODES + i];
        nn[11] = w4[4 * N_NODES + i];
#pragma unroll
        for (int j = 0; j < 12; ++j) {
            const int nd = nn[j];
            atomicAdd(&row[nd >> 2], 1u << ((nd & 3) * 8));
        }
    }
    __syncthreads();
    if (t < N_GRAPHS) { const int hv = hist[t]; if (hv) atomicAdd(&counts[t], hv); }
}

__device__ inline unsigned pack_bf16(unsigned a, unsigned b) {
    // exact: u8 -> f32 -> truncate to bf16 (u8 mantissa fits in bf16)
    return (__builtin_bit_cast(unsigned, (float)a) >> 16) |
           (__builtin_bit_cast(unsigned, (float)b) & 0xFFFF0000u);
}

// ---------------------------------------------------------------------------
// Repack u8 counts into MFMA A-fragment order:
// Apack[(kp*4 + mt)*64 + lane] = 8 bf16 of row (mt*32 + lane&31),
// k = kp*16 + 8*(lane>>5) + 0..7.
// ---------------------------------------------------------------------------
__global__ __launch_bounds__(256)
void c8_to_apack_kernel(const unsigned char* __restrict__ C8,
                        uint4* __restrict__ Apack) {
    const int kp = blockIdx.x;           // 0..NPANEL-1
    const int t = threadIdx.x;
    const int mt = t >> 6;
    const int l = t & 63;
    const int row = mt * 32 + (l & 31);
    const int k0 = kp * 16 + 8 * (l >> 5);
    const uint2 b = *(const uint2*)(C8 + (size_t)row * KPAD + k0);
    uint4 o;
    o.x = pack_bf16(b.x & 0xFFu, (b.x >> 8) & 0xFFu);
    o.y = pack_bf16((b.x >> 16) & 0xFFu, b.x >> 24);
    o.z = pack_bf16(b.y & 0xFFu, (b.y >> 8) & 0xFFu);
    o.w = pack_bf16((b.y >> 16) & 0xFFu, b.y >> 24);
    Apack[(size_t)(kp * 4 + mt) * 64 + l] = o;
}

// ---------------------------------------------------------------------------
// B-load: 16 global dwords per step per lane, straight into VGPRs in the
// exact MFMA B-fragment layout (k = 8h+j, n = lane&31; two 32-col groups).
// Each wave-instr covers 2 full 128B lines. GUARD clamps k for the tail
// split (A is zero there, so clamped values contribute nothing).
// ---------------------------------------------------------------------------
template <int GUARD>
__device__ inline void issue_b(const float* __restrict__ xp, int krow,
                               unsigned (&u)[16]) {
#pragma unroll
    for (int j = 0; j < 8; ++j) {
        int k = krow + j;
        if (GUARD) k = min(k, N_NODES - 1);
        const float* p = xp + (size_t)k * HID;
        u[j]     = __builtin_bit_cast(unsigned, p[0]);
        u[8 + j] = __builtin_bit_cast(unsigned, p[32]);
    }
}

__device__ inline f32x16 mfma_bf16(bf16x8 a, bf16x8 b, f32x16 c) {
    return __builtin_amdgcn_mfma_f32_32x32x16_bf16(a, b, c, 0, 0, 0);
}

// one v_perm per dword: [b0,b1]=u0.bytes[2,3], [b2,b3]=u1.bytes[2,3]
__device__ inline unsigned bpack(unsigned u0, unsigned u1) {
    return __builtin_amdgcn_perm(u1, u0, 0x07060302u);
}

__device__ inline void step_mfma(const unsigned (&u)[16], const uint4 (&a)[2],
                                 f32x16 (&acc)[2][2]) {
    unsigned d0[4], d1[4];
#pragma unroll
    for (int jj = 0; jj < 4; ++jj) {
        d0[jj] = bpack(u[2 * jj], u[2 * jj + 1]);
        d1[jj] = bpack(u[8 + 2 * jj], u[8 + 2 * jj + 1]);
    }
    const bf16x8 b0 = __builtin_bit_cast(bf16x8, make_uint4(d0[0], d0[1], d0[2], d0[3]));
    const bf16x8 b1 = __builtin_bit_cast(bf16x8, make_uint4(d1[0], d1[1], d1[2], d1[3]));
    const bf16x8 a0 = __builtin_bit_cast(bf16x8, a[0]);
    const bf16x8 a1 = __builtin_bit_cast(bf16x8, a[1]);
    acc[0][0] = mfma_bf16(a0, b0, acc[0][0]);
    acc[0][1] = mfma_bf16(a0, b1, acc[0][1]);
    acc[1][0] = mfma_bf16(a1, b0, acc[1][0]);
    acc[1][1] = mfma_bf16(a1, b1, acc[1][1]);
}

// 3-deep register software pipeline over NSTEP k-steps: every wave keeps
// ~54 loads (12 KB) in flight continuously — no barriers, no LDS staging.
template <int GUARD>
__device__ inline void run_k(const float* __restrict__ xp,
                             const uint4* __restrict__ Apack,
                             int kbase, int h, int lane, int rm,
                             f32x16 (&acc)[2][2]) {
    unsigned bu[3][16];
    uint4 au[3][2];
    const int kp0 = kbase >> 4;
#pragma unroll
    for (int s = 0; s < 3; ++s) {
        issue_b<GUARD>(xp, kbase + s * 16 + 8 * h, bu[s]);
        au[s][0] = Apack[(size_t)((kp0 + s) * 4 + rm * 2) * 64 + lane];
        au[s][1] = Apack[(size_t)((kp0 + s) * 4 + rm * 2 + 1) * 64 + lane];
    }
#pragma unroll
    for (int s = 0; s < NSTEP; ++s) {
        const int slot = s % 3;
        step_mfma(bu[slot], au[slot], acc);
        if (s + 3 < NSTEP) {
            issue_b<GUARD>(xp, kbase + (s + 3) * 16 + 8 * h, bu[slot]);
            au[slot][0] = Apack[(size_t)((kp0 + s + 3) * 4 + rm * 2) * 64 + lane];
            au[slot][1] = Apack[(size_t)((kp0 + s + 3) * 4 + rm * 2 + 1) * 64 + lane];
        }
    }
}

// ---------------------------------------------------------------------------
// Barrier-free-K split-K MFMA GEMM. grid=(16 regions, KS2), block=256.
// Region = (rm: 64-graph half, rn: 64-col slice). The 4 waves of a block
// take 4 consecutive k-splits of KSPAN=288 and are reduced in LDS at the
// end -> one part slice per block-row (44 total, 11.5 MB).
// ---------------------------------------------------------------------------
template <int ATOMIC>
__global__ __launch_bounds__(256, 3)
void pool_gemm5_kernel(const float* __restrict__ x,
                       const uint4* __restrict__ Apack,
                       float* __restrict__ dst) {
    __shared__ float red[3][2][64 * 16];     // 24 KB
    const int t = threadIdx.x;
    const int lane = t & 63;
    const int w = t >> 6;
    const int n = lane & 31;
    const int h = lane >> 5;
    const int region = blockIdx.x;
    const int rm = region & 1;
    const int rn = region >> 1;
    const int ks = blockIdx.y * 4 + w;
    const int kbase = ks * KSPAN;

    f32x16 acc[2][2];
#pragma unroll
    for (int p = 0; p < 2; ++p)
#pragma unroll
        for (int q = 0; q < 2; ++q)
#pragma unroll
            for (int r = 0; r < 16; ++r) acc[p][q][r] = 0.f;

    const float* xp = x + rn * 64 + n;       // column base for this lane

    if (kbase + KSPAN <= N_NODES) {
        run_k<0>(xp, Apack, kbase, h, lane, rm, acc);
    } else if (kbase < N_NODES) {
        run_k<1>(xp, Apack, kbase, h, lane, rm, acc);
    }
    // fully-OOB waves: acc stays 0, still join the barriers below

    float* outp = ATOMIC ? dst : dst + (size_t)blockIdx.y * (N_GRAPHS * HID);
#pragma unroll
    for (int p = 0; p < 2; ++p) {
        __syncthreads();
        if (w > 0) {
#pragma unroll
            for (int q = 0; q < 2; ++q)
#pragma unroll
                for (int i = 0; i < 16; ++i)
                    red[w - 1][q][i * 64 + lane] = acc[p][q][i];
        }
        __syncthreads();
        if (w == 0) {
#pragma unroll
            for (int q = 0; q < 2; ++q)
#pragma unroll
                for (int i = 0; i < 16; ++i) {
                    const float v = acc[p][q][i] + red[0][q][i * 64 + lane] +
                                    red[1][q][i * 64 + lane] + red[2][q][i * 64 + lane];
                    // C/D layout: col=lane&31, row=(i&3)+8*(i>>2)+4*h
                    const int row = rm * 64 + p * 32 + (i & 3) + 8 * (i >> 2) + 4 * h;
                    const int col = rn * 64 + q * 32 + n;
                    if (ATOMIC) atomicAdd(&outp[(size_t)row * HID + col], v);
                    else        outp[(size_t)row * HID + col] = v;
                }
        }
    }
}

// ---------------------------------------------------------------------------
// Psum = sum over KS2 partials (coalesced streams)
// ---------------------------------------------------------------------------
__global__ __launch_bounds__(256)
void reduce_part_kernel(const float* __restrict__ part, float* __restrict__ Psum) {
    const int id = blockIdx.x * 256 + threadIdx.x;
    float s0 = 0.f, s1 = 0.f;
    for (int k = 0; k + 2 <= KS2; k += 2) {
        s0 += part[(size_t)k * (N_GRAPHS * HID) + id];
        s1 += part[(size_t)(k + 1) * (N_GRAPHS * HID) + id];
    }
    Psum[id] = s0 + s1;
}

// ---------------------------------------------------------------------------
// out[r][c] += sum_k A[r][k] * W[k][c]  (+ 12*mask(r)*bias[c] on k-chunk 0)
// ---------------------------------------------------------------------------
__global__ __launch_bounds__(256)
void layer_gemm_kernel(const float* __restrict__ A, int lda, int scaleA,
                       const float* __restrict__ W,
                       const float* __restrict__ bias,
                       const int* __restrict__ counts,
                       float* __restrict__ out) {
    __shared__ float Alds[16][128];
    const int ct = blockIdx.x, rt = blockIdx.y, ksb = blockIdx.z;
    const int t = threadIdx.x;
    const int cc = ct * 64 + (t & 63);
    const int wv = t >> 6;
    const int k0 = ksb * 128;

    for (int idx = t; idx < 16 * 32; idx += 256) {
        const int rr = idx >> 5;
        const int kk = (idx & 31) * 4;
        const int row = rt * 16 + rr;
        float4 v = *(const float4*)&A[(size_t)row * lda + k0 + kk];
        if (scaleA) {
            const float inv = 1.f / (float)max(counts[row], 1);
            v.x *= inv; v.y *= inv; v.z *= inv; v.w *= inv;
        }
        *(float4*)&Alds[rr][kk] = v;
    }
    __syncthreads();

    const int r0 = rt * 16 + wv * 4;
    float a0 = 0.f, a1 = 0.f, a2 = 0.f, a3 = 0.f;
#pragma unroll 8
    for (int k = 0; k < 128; ++k) {
        const float wval = W[(size_t)(k0 + k) * HID + cc];
        a0 += Alds[wv * 4 + 0][k] * wval;
        a1 += Alds[wv * 4 + 1][k] * wval;
        a2 += Alds[wv * 4 + 2][k] * wval;
        a3 += Alds[wv * 4 + 3][k] * wval;
    }
    if (ksb == 0) {
        const float bc = bias[cc];
        a0 += (counts[r0 + 0] > 0 ? 12.f : 0.f) * bc;
        a1 += (counts[r0 + 1] > 0 ? 12.f : 0.f) * bc;
        a2 += (counts[r0 + 2] > 0 ? 12.f : 0.f) * bc;
        a3 += (counts[r0 + 3] > 0 ? 12.f : 0.f) * bc;
    }
    atomicAdd(&out[(size_t)(r0 + 0) * 1536 + cc], a0);
    atomicAdd(&out[(size_t)(r0 + 1) * 1536 + cc], a1);
    atomicAdd(&out[(size_t)(r0 + 2) * 1536 + cc], a2);
    atomicAdd(&out[(size_t)(r0 + 3) * 1536 + cc], a3);
}

extern "C" void kernel_launch(void* const* d_in, const int* in_sizes, int n_in,
                              void* d_out, int out_size, void* d_ws, size_t ws_size,
                              hipStream_t stream) {
    const float* x     = (const float*)d_in[0];
    const int*   w2    = (const int*)d_in[1];
    const int*   w3    = (const int*)d_in[2];
    const int*   w4    = (const int*)d_in[3];
    const int*   batch = (const int*)d_in[4];
    const float* W0    = (const float*)d_in[5];
    const float* b0    = (const float*)d_in[6];
    const float* W1    = (const float*)d_in[7];
    const float* b1    = (const float*)d_in[8];
    const float* W2    = (const float*)d_in[9];
    const float* b2    = (const float*)d_in[10];
    float* out = (float*)d_out;

    unsigned char* ws  = (unsigned char*)d_ws;
    unsigned int* C32  = (unsigned int*)(ws + C8_OFF);
    float* Psum        = (float*)(ws + PSUM_OFF);
    int* counts        = (int*)(ws + COUNTS_OFF);
    uint4* Apack       = (uint4*)(ws + APACK_OFF);
    float* part        = (float*)(ws + PART_OFF);
    const bool use_part = ws_size >= PART_OFF + PART_BYTES;

    hipMemsetAsync(d_ws, 0, ZERO_BYTES, stream);      // C8 + Psum + counts
    hipMemsetAsync(d_out, 0, (size_t)out_size * 4, stream);

    build_c_kernel<<<(N_NODES + 255) / 256, 256, 0, stream>>>(w2, w3, w4, batch, C32, counts);
    c8_to_apack_kernel<<<NPANEL, 256, 0, stream>>>((const unsigned char*)C32, Apack);

    if (use_part) {
        pool_gemm5_kernel<0><<<dim3(16, KS2), 256, 0, stream>>>(x, Apack, part);
        reduce_part_kernel<<<256, 256, 0, stream>>>(part, Psum);
    } else {
        pool_gemm5_kernel<1><<<dim3(16, KS2), 256, 0, stream>>>(x, Apack, Psum);
    }

    layer_gemm_kernel<<<dim3(8, 8, 4), 256, 0, stream>>>(Psum, HID, 1, W0, b0, counts, out);
    layer_gemm_kernel<<<dim3(8, 8, 4), 256, 0, stream>>>(out, 1536, 0, W1, b1, counts, out + 512);
    layer_gemm_kernel<<<dim3(8, 8, 4), 256, 0, stream>>>(out + 512, 1536, 0, W2, b2, counts, out + 1024);
}